// Round 2
// baseline (196.836 us; speedup 1.0000x reference)
//
#include <hip/hip_runtime.h>

#define EPSV 1e-5f

// Workspace layout (floats):
//   kbuf @ 0     : [b][g][c][l]  8*4*8*49 = 12544
//   W    @ 12544 : [b][g][o<74][c<8]      = 18944   (W = proj_w @ k^T)
//   wqT  @ 31488 : [i][o] 32*32           = 1024
//   dyT  @ 32512 : [i][o] 64*64           = 4096
//   val  @ 40960 : [b][ch64][h][w]        = 2097152 (8 MB)
#define OFF_W    12544
#define OFF_WQT  31488
#define OFF_DYT  32512
#define OFF_VAL  40960

typedef float f4u __attribute__((ext_vector_type(4), aligned(4)));

// ---------------------------------------------------------------------------
// Blocks 0..55: pool kctx (ch 32..63) to 7x7, wk conv1x1 + BN.
// Blocks 56..75: weight transposes (wqT, dyT).
// ---------------------------------------------------------------------------
__global__ __launch_bounds__(256) void pool_prep_kernel(
    const float* __restrict__ x,
    const float* __restrict__ wk_w, const float* __restrict__ wk_g,
    const float* __restrict__ wk_b, const float* __restrict__ wk_m,
    const float* __restrict__ wk_v,
    const float* __restrict__ wq_w, const float* __restrict__ dy_w,
    float* __restrict__ ws)
{
  const int bid = blockIdx.x;
  const int tid = threadIdx.x;

  if (bid >= 56) {
    const int t = (bid - 56) * 256 + tid;
    float* wqT = ws + OFF_WQT;
    float* dyT = ws + OFF_DYT;
    if (t < 1024) {
      const int i = t >> 5, o = t & 31;
      wqT[t] = wq_w[o * 32 + i];
    } else {
      const int t2 = t - 1024;  // 0..4095
      const int i = t2 >> 6, o = t2 & 63;
      dyT[t2] = dy_w[o * 64 + i];
    }
    return;
  }

  float* kbuf = ws;
  const int b = bid / 7;
  const int p = bid % 7;
  __shared__ float s_tmp[32 * 64];
  __shared__ float s_kp[32 * 7];

  const int sh = (p * 64) / 7, eh = ((p + 1) * 64 + 6) / 7;
  const float invH = 1.0f / (float)(eh - sh);
  for (int idx = tid; idx < 2048; idx += 256) {
    const int c = idx >> 6, ww = idx & 63;
    const float* xp = x + ((size_t)(b * 64 + 32 + c)) * 4096 + ww;
    float s = 0.f;
    for (int hh = sh; hh < eh; ++hh) s += xp[hh * 64];
    s_tmp[idx] = s * invH;
  }
  __syncthreads();
  if (tid < 224) {
    const int c = tid / 7, q = tid % 7;
    const int sw = (q * 64) / 7, ew = ((q + 1) * 64 + 6) / 7;
    float s = 0.f;
    for (int ww = sw; ww < ew; ++ww) s += s_tmp[c * 64 + ww];
    s_kp[c * 7 + q] = s / (float)(ew - sw);
  }
  __syncthreads();
  if (tid < 224) {
    const int o = tid / 7, q = tid % 7;
    float s = 0.f;
#pragma unroll
    for (int i = 0; i < 32; i++) s += wk_w[o * 32 + i] * s_kp[i * 7 + q];
    const float sc = wk_g[o] * rsqrtf(wk_v[o] + EPSV);
    const int g = o >> 3, c = o & 7, l = p * 7 + q;
    kbuf[(((size_t)b * 4 + g) * 8 + c) * 49 + l] =
        (s - wk_m[o]) * sc + wk_b[o];
  }
}

// ---------------------------------------------------------------------------
// W[bg][o][c] = sum_l proj_w[o][l] * k[bg][c][l].  32 blocks, 256 threads.
// ---------------------------------------------------------------------------
__global__ __launch_bounds__(256) void fold_w_kernel(
    const float* __restrict__ proj_w, const float* __restrict__ ws_in,
    float* __restrict__ Wout)
{
  const int bg = blockIdx.x;
  const int tid = threadIdx.x;
  __shared__ float s_k[392];
  for (int i = tid; i < 392; i += 256) s_k[i] = ws_in[(size_t)bg * 392 + i];
  __syncthreads();
  for (int idx = tid; idx < 592; idx += 256) {
    const int o = idx >> 3, c = idx & 7;
    float s = 0.f;
#pragma unroll
    for (int l = 0; l < 49; l++) s += proj_w[o * 49 + l] * s_k[c * 49 + l];
    Wout[(size_t)bg * 592 + idx] = s;
  }
}

// ---------------------------------------------------------------------------
// Attention kernel. 1024 blocks = 8b x 64h x 2branch, 256 threads = 4 heads
// (wave-uniform) x 64 cols. Branch is block-uniform -> no intra-block
// imbalance. Only one barrier (LDS staging). Writes val to ws.
// ---------------------------------------------------------------------------
__global__ __launch_bounds__(256) void attn_kernel(
    const float* __restrict__ x,
    const float* __restrict__ wq_g, const float* __restrict__ wq_b,
    const float* __restrict__ wq_m, const float* __restrict__ wq_v,
    const float* __restrict__ proj_b,
    const float* __restrict__ rpb1, const float* __restrict__ rpb2,
    const float* __restrict__ ws,
    float* __restrict__ vbuf)
{
  __shared__ float s_rpb[4 * 169];
  __shared__ float s_xq[32 * 64];  // q-input row: x[0:32][h][:]

  const int bid = blockIdx.x;
  const int br = bid & 1;
  const int h = (bid >> 1) & 63;
  const int b = bid >> 7;
  const int tid = threadIdx.x;
  const int w = tid & 63;
  const int gu = __builtin_amdgcn_readfirstlane(tid >> 6);  // 0..3

  const float* xb = x + (size_t)b * 64 * 4096;

  // stage q-input row (shared by all 4 heads) + branch rpb
  for (int idx = tid; idx < 2048; idx += 256) {
    const int c = idx >> 6, ww = idx & 63;
    s_xq[idx] = xb[c * 4096 + h * 64 + ww];
  }
  if (br == 0) {
    for (int i = tid; i < 324; i += 256) s_rpb[i] = rpb1[i];
  } else {
    for (int i = tid; i < 676; i += 256) s_rpb[i] = rpb2[i];
  }
  __syncthreads();

  // ---- q = BN(wq @ x[0:32]) * SCALE ----
  float q8[8];
#pragma unroll
  for (int o = 0; o < 8; o++) q8[o] = 0.f;
  {
    const float* wqt = ws + OFF_WQT + gu * 8;
#pragma unroll
    for (int i = 0; i < 32; i++) {
      const float xv = s_xq[i * 64 + w];
#pragma unroll
      for (int o = 0; o < 8; o++) q8[o] += wqt[i * 32 + o] * xv;
    }
#pragma unroll
    for (int o = 0; o < 8; o++) {
      const int oc = gu * 8 + o;
      const float s = wq_g[oc] * rsqrtf(wq_v[oc] + EPSV);
      q8[o] = (q8[o] * s + (wq_b[oc] - wq_m[oc] * s)) * 0.25f;
    }
  }

  const float* Wr = ws + OFF_W + (size_t)(b * 4 + gu) * 592;  // uniform

  const int ph = 63 - h, pw = 63 - w;

  if (br == 0) {
    // ===== attn1 (5x5) =====
    const int bih5 = ph - min(max(ph - 2, 0), 59);
    const int biw5 = pw - min(max(pw - 2, 0), 59);
    const int si5 = min(max(h - 2, 0), 59), sj5 = min(max(w - 2, 0), 59);
    float l1[25];
#pragma unroll
    for (int o = 0; o < 25; o++) {
      const float* wo = Wr + o * 8;
      float s = proj_b[o];
#pragma unroll
      for (int c = 0; c < 8; c++) s += wo[c] * q8[c];
      l1[o] = s;
    }
    const float* rp1 = s_rpb + gu * 81 + bih5 * 9 + biw5;
#pragma unroll
    for (int ki = 0; ki < 5; ki++)
#pragma unroll
      for (int kj = 0; kj < 5; kj++) l1[ki * 5 + kj] += rp1[ki * 9 + kj];

    float mx = l1[0];
#pragma unroll
    for (int o = 1; o < 25; o++) mx = fmaxf(mx, l1[o]);
    float sum = 0.f;
#pragma unroll
    for (int o = 0; o < 25; o++) {
      const float e = __expf(l1[o] - mx);
      l1[o] = e;
      sum += e;
    }
    const float inv = 1.f / sum;

    float acc[8];
#pragma unroll
    for (int c = 0; c < 8; c++) acc[c] = 0.f;
    const float* vb = xb + gu * 8 * 4096;
#pragma unroll
    for (int i = 0; i < 5; i++) {
      const float a0 = l1[i * 5 + 0], a1 = l1[i * 5 + 1], a2 = l1[i * 5 + 2];
      const float a3 = l1[i * 5 + 3], a4 = l1[i * 5 + 4];
      const float* vr0 = vb + (si5 + i) * 64 + sj5;
#pragma unroll
      for (int c = 0; c < 8; c++) {
        const float* vr = vr0 + c * 4096;
        const f4u f = *(const f4u*)vr;
        const float v4 = vr[4];
        acc[c] += a0 * f.x + a1 * f.y + a2 * f.z + a3 * f.w + a4 * v4;
      }
    }
#pragma unroll
    for (int c = 0; c < 8; c++)
      vbuf[((size_t)(b * 64 + gu * 8 + c)) * 4096 + h * 64 + w] = acc[c] * inv;
  } else {
    // ===== attn2 (7x7) =====
    const int bih7 = ph - min(max(ph - 3, 0), 57);
    const int biw7 = pw - min(max(pw - 3, 0), 57);
    const int si7 = min(max(h - 3, 0), 57), sj7 = min(max(w - 3, 0), 57);
    float l2[49];
#pragma unroll
    for (int o = 0; o < 49; o++) {
      const float* wo = Wr + (25 + o) * 8;
      float s = proj_b[25 + o];
#pragma unroll
      for (int c = 0; c < 8; c++) s += wo[c] * q8[c];
      l2[o] = s;
    }
    const float* rp2 = s_rpb + gu * 169 + bih7 * 13 + biw7;
#pragma unroll
    for (int ki = 0; ki < 7; ki++)
#pragma unroll
      for (int kj = 0; kj < 7; kj++) l2[ki * 7 + kj] += rp2[ki * 13 + kj];

    float mx = l2[0];
#pragma unroll
    for (int o = 1; o < 49; o++) mx = fmaxf(mx, l2[o]);
    float sum = 0.f;
#pragma unroll
    for (int o = 0; o < 49; o++) {
      const float e = __expf(l2[o] - mx);
      l2[o] = e;
      sum += e;
    }
    const float inv = 1.f / sum;

    float acc[8];
#pragma unroll
    for (int c = 0; c < 8; c++) acc[c] = 0.f;
    const float* vb = xb + (32 + gu * 8) * 4096;
#pragma unroll
    for (int i = 0; i < 7; i++) {
      const float a0 = l2[i * 7 + 0], a1 = l2[i * 7 + 1], a2 = l2[i * 7 + 2];
      const float a3 = l2[i * 7 + 3], a4 = l2[i * 7 + 4], a5 = l2[i * 7 + 5];
      const float a6 = l2[i * 7 + 6];
      const float* vr0 = vb + (si7 + i) * 64 + sj7;
#pragma unroll
      for (int c = 0; c < 8; c++) {
        const float* vr = vr0 + c * 4096;
        const f4u fa = *(const f4u*)vr;        // j 0..3
        const f4u fb = *(const f4u*)(vr + 3);  // j 3..6
        acc[c] += a0 * fa.x + a1 * fa.y + a2 * fa.z + a3 * fa.w +
                  a4 * fb.y + a5 * fb.z + a6 * fb.w;
      }
    }
#pragma unroll
    for (int c = 0; c < 8; c++)
      vbuf[((size_t)(b * 64 + 32 + gu * 8 + c)) * 4096 + h * 64 + w] =
          acc[c] * inv;
  }
}

// ---------------------------------------------------------------------------
// Final conv1x1 (64->64) + BN. 512 blocks = 8b x 64h, 512 threads = 8 og x
// 64 w. Identical arithmetic to the previous fused epilogue.
// ---------------------------------------------------------------------------
__global__ __launch_bounds__(512) void final_conv_kernel(
    const float* __restrict__ vbuf,
    const float* __restrict__ dy_g, const float* __restrict__ dy_b,
    const float* __restrict__ dy_m, const float* __restrict__ dy_v,
    const float* __restrict__ ws,
    float* __restrict__ out)
{
  __shared__ float s_val[64 * 64];  // [ch][w]

  const int bx = blockIdx.x;
  const int b = bx >> 6;
  const int h = bx & 63;
  const int tid = threadIdx.x;
  const int w = tid & 63;
  const int ogu = __builtin_amdgcn_readfirstlane(tid >> 6);  // 0..7

  // stage val[b][:][h][:]  (4096 floats, f4 coalesced)
  for (int idx4 = tid; idx4 < 1024; idx4 += 512) {
    const int ic = idx4 >> 4, w4 = idx4 & 15;
    *(f4u*)&s_val[ic * 64 + w4 * 4] =
        *(const f4u*)&vbuf[((size_t)(b * 64 + ic)) * 4096 + h * 64 + w4 * 4];
  }
  __syncthreads();

  float facc[8];
#pragma unroll
  for (int oo = 0; oo < 8; oo++) facc[oo] = 0.f;
  const float* dyt = ws + OFF_DYT + ogu * 8;
#pragma unroll
  for (int i = 0; i < 64; i++) {
    const float v = s_val[i * 64 + w];
#pragma unroll
    for (int oo = 0; oo < 8; oo++) facc[oo] += dyt[i * 64 + oo] * v;
  }
#pragma unroll
  for (int oo = 0; oo < 8; oo++) {
    const int oc = ogu * 8 + oo;
    const float sc = dy_g[oc] * rsqrtf(dy_v[oc] + EPSV);
    out[((size_t)(b * 64 + oc)) * 4096 + h * 64 + w] =
        (facc[oo] - dy_m[oc]) * sc + dy_b[oc];
  }
}

// ---------------------------------------------------------------------------
extern "C" void kernel_launch(void* const* d_in, const int* in_sizes, int n_in,
                              void* d_out, int out_size, void* d_ws, size_t ws_size,
                              hipStream_t stream)
{
  const float* x      = (const float*)d_in[0];
  const float* wq_w   = (const float*)d_in[1];
  const float* wq_g   = (const float*)d_in[2];
  const float* wq_b   = (const float*)d_in[3];
  const float* wq_m   = (const float*)d_in[4];
  const float* wq_v   = (const float*)d_in[5];
  const float* wk_w   = (const float*)d_in[6];
  const float* wk_g   = (const float*)d_in[7];
  const float* wk_b   = (const float*)d_in[8];
  const float* wk_m   = (const float*)d_in[9];
  const float* wk_v   = (const float*)d_in[10];
  const float* proj_w = (const float*)d_in[11];
  const float* proj_b = (const float*)d_in[12];
  const float* rpb1   = (const float*)d_in[13];
  const float* rpb2   = (const float*)d_in[14];
  const float* dy_w   = (const float*)d_in[15];
  const float* dy_g   = (const float*)d_in[16];
  const float* dy_b   = (const float*)d_in[17];
  const float* dy_m   = (const float*)d_in[18];
  const float* dy_v   = (const float*)d_in[19];

  float* ws = (float*)d_ws;

  pool_prep_kernel<<<76, 256, 0, stream>>>(x, wk_w, wk_g, wk_b, wk_m, wk_v,
                                           wq_w, dy_w, ws);
  fold_w_kernel<<<32, 256, 0, stream>>>(proj_w, ws, ws + OFF_W);
  attn_kernel<<<1024, 256, 0, stream>>>(x, wq_g, wq_b, wq_m, wq_v,
                                        proj_b, rpb1, rpb2,
                                        ws, ws + OFF_VAL);
  final_conv_kernel<<<512, 512, 0, stream>>>(ws + OFF_VAL,
                                             dy_g, dy_b, dy_m, dy_v,
                                             ws, (float*)d_out);
}

// Round 3
// 165.784 us; speedup vs baseline: 1.1873x; 1.1873x over previous
//
#include <hip/hip_runtime.h>

#define EPSV 1e-5f

// Workspace layout (floats):
//   kbuf @ 0     : [b][g][c][l]  8*4*8*49 = 12544
//   W    @ 12544 : [b][g][o<74][c<8]      = 18944   (W = proj_w @ k^T)
//   wqT  @ 31488 : [i][o] 32*32           = 1024
//   dyT  @ 32512 : [i][o] 64*64           = 4096
#define OFF_W    12544
#define OFF_WQT  31488
#define OFF_DYT  32512

typedef float f4u __attribute__((ext_vector_type(4), aligned(4)));

// Tree reductions (depth ~6 instead of serial 25/49 chains).
// max tree is exactly associative; sum tree reorders adds (last-ulp only).
#define FMAXOP(a, b) fmaxf((a), (b))
#define FADDOP(a, b) ((a) + (b))

#define TREE25(op, arr, res)                                         \
  {                                                                  \
    float u_[13];                                                    \
    _Pragma("unroll") for (int i_ = 0; i_ < 12; i_++)                \
        u_[i_] = op(arr[i_], arr[i_ + 12]);                          \
    u_[12] = arr[24];                                                \
    _Pragma("unroll") for (int i_ = 0; i_ < 6; i_++)                 \
        u_[i_] = op(u_[i_], u_[i_ + 6]);                             \
    _Pragma("unroll") for (int i_ = 0; i_ < 3; i_++)                 \
        u_[i_] = op(u_[i_], u_[i_ + 3]);                             \
    res = op(op(op(u_[0], u_[1]), u_[2]), u_[12]);                   \
  }

#define TREE49(op, arr, res)                                         \
  {                                                                  \
    float u_[25];                                                    \
    _Pragma("unroll") for (int i_ = 0; i_ < 24; i_++)                \
        u_[i_] = op(arr[i_], arr[i_ + 24]);                          \
    u_[24] = arr[48];                                                \
    _Pragma("unroll") for (int i_ = 0; i_ < 12; i_++)                \
        u_[i_] = op(u_[i_], u_[i_ + 12]);                            \
    _Pragma("unroll") for (int i_ = 0; i_ < 6; i_++)                 \
        u_[i_] = op(u_[i_], u_[i_ + 6]);                             \
    _Pragma("unroll") for (int i_ = 0; i_ < 3; i_++)                 \
        u_[i_] = op(u_[i_], u_[i_ + 3]);                             \
    res = op(op(op(u_[0], u_[1]), u_[2]), u_[24]);                   \
  }

// ---------------------------------------------------------------------------
// Blocks 0..55: pool kctx (ch 32..63) to 7x7, wk conv1x1 + BN.
// Blocks 56..75: weight transposes (wqT, dyT).
// ---------------------------------------------------------------------------
__global__ __launch_bounds__(256) void pool_prep_kernel(
    const float* __restrict__ x,
    const float* __restrict__ wk_w, const float* __restrict__ wk_g,
    const float* __restrict__ wk_b, const float* __restrict__ wk_m,
    const float* __restrict__ wk_v,
    const float* __restrict__ wq_w, const float* __restrict__ dy_w,
    float* __restrict__ ws)
{
  const int bid = blockIdx.x;
  const int tid = threadIdx.x;

  if (bid >= 56) {
    const int t = (bid - 56) * 256 + tid;
    float* wqT = ws + OFF_WQT;
    float* dyT = ws + OFF_DYT;
    if (t < 1024) {
      const int i = t >> 5, o = t & 31;
      wqT[t] = wq_w[o * 32 + i];
    } else {
      const int t2 = t - 1024;  // 0..4095
      const int i = t2 >> 6, o = t2 & 63;
      dyT[t2] = dy_w[o * 64 + i];
    }
    return;
  }

  float* kbuf = ws;
  const int b = bid / 7;
  const int p = bid % 7;
  __shared__ float s_tmp[32 * 64];
  __shared__ float s_kp[32 * 7];

  const int sh = (p * 64) / 7, eh = ((p + 1) * 64 + 6) / 7;
  const float invH = 1.0f / (float)(eh - sh);
  for (int idx = tid; idx < 2048; idx += 256) {
    const int c = idx >> 6, ww = idx & 63;
    const float* xp = x + ((size_t)(b * 64 + 32 + c)) * 4096 + ww;
    float s = 0.f;
    for (int hh = sh; hh < eh; ++hh) s += xp[hh * 64];
    s_tmp[idx] = s * invH;
  }
  __syncthreads();
  if (tid < 224) {
    const int c = tid / 7, q = tid % 7;
    const int sw = (q * 64) / 7, ew = ((q + 1) * 64 + 6) / 7;
    float s = 0.f;
    for (int ww = sw; ww < ew; ++ww) s += s_tmp[c * 64 + ww];
    s_kp[c * 7 + q] = s / (float)(ew - sw);
  }
  __syncthreads();
  if (tid < 224) {
    const int o = tid / 7, q = tid % 7;
    float s = 0.f;
#pragma unroll
    for (int i = 0; i < 32; i++) s += wk_w[o * 32 + i] * s_kp[i * 7 + q];
    const float sc = wk_g[o] * rsqrtf(wk_v[o] + EPSV);
    const int g = o >> 3, c = o & 7, l = p * 7 + q;
    kbuf[(((size_t)b * 4 + g) * 8 + c) * 49 + l] =
        (s - wk_m[o]) * sc + wk_b[o];
  }
}

// ---------------------------------------------------------------------------
// W[bg][o][c] = sum_l proj_w[o][l] * k[bg][c][l].  32 blocks, 256 threads.
// ---------------------------------------------------------------------------
__global__ __launch_bounds__(256) void fold_w_kernel(
    const float* __restrict__ proj_w, const float* __restrict__ ws_in,
    float* __restrict__ Wout)
{
  const int bg = blockIdx.x;
  const int tid = threadIdx.x;
  __shared__ float s_k[392];
  for (int i = tid; i < 392; i += 256) s_k[i] = ws_in[(size_t)bg * 392 + i];
  __syncthreads();
  for (int idx = tid; idx < 592; idx += 256) {
    const int o = idx >> 3, c = idx & 7;
    float s = 0.f;
#pragma unroll
    for (int l = 0; l < 49; l++) s += proj_w[o * 49 + l] * s_k[c * 49 + l];
    Wout[(size_t)bg * 592 + idx] = s;
  }
}

// ---------------------------------------------------------------------------
// Fused main (round-0 structure). Block = 512 = 2 branches x 4 heads x 64
// cols, one row. Both halves compute q independently (no barrier — the r1
// q-share experiment showed the sync latency costs more than the 256 FMA).
// Softmax uses tree max/sum (depth 6) + independent exp batch for ILP.
// ---------------------------------------------------------------------------
__global__ __launch_bounds__(512, 4) void contmix_main(
    const float* __restrict__ x,
    const float* __restrict__ wq_g, const float* __restrict__ wq_b,
    const float* __restrict__ wq_m, const float* __restrict__ wq_v,
    const float* __restrict__ proj_b,
    const float* __restrict__ rpb1, const float* __restrict__ rpb2,
    const float* __restrict__ dy_g, const float* __restrict__ dy_b,
    const float* __restrict__ dy_m, const float* __restrict__ dy_v,
    const float* __restrict__ ws,
    float* __restrict__ out)
{
  __shared__ float s_rpb1[4 * 81];
  __shared__ float s_rpb2[4 * 169];
  __shared__ float s_val[64 * 64];  // [ch][w]

  const int bx = blockIdx.x;
  const int b = bx >> 6;
  const int h = bx & 63;
  const int tid = threadIdx.x;
  const int w = tid & 63;
  const int bru = __builtin_amdgcn_readfirstlane(tid >> 8);
  const int gu  = __builtin_amdgcn_readfirstlane((tid >> 6) & 3);

  for (int i = tid; i < 324; i += 512) s_rpb1[i] = rpb1[i];
  for (int i = tid; i < 676; i += 512) s_rpb2[i] = rpb2[i];
  __syncthreads();

  const float* xb = x + (size_t)b * 64 * 4096;

  // ---- q = BN(wq @ x[0:32]) * SCALE ----
  float q8[8];
#pragma unroll
  for (int o = 0; o < 8; o++) q8[o] = 0.f;
  {
    const float* wqt = ws + OFF_WQT + gu * 8;
#pragma unroll
    for (int i = 0; i < 32; i++) {
      const float xv = xb[i * 4096 + h * 64 + w];
#pragma unroll
      for (int o = 0; o < 8; o++) q8[o] += wqt[i * 32 + o] * xv;
    }
#pragma unroll
    for (int o = 0; o < 8; o++) {
      const int oc = gu * 8 + o;
      const float s = wq_g[oc] * rsqrtf(wq_v[oc] + EPSV);
      q8[o] = (q8[o] * s + (wq_b[oc] - wq_m[oc] * s)) * 0.25f;
    }
  }

  const float* Wr = ws + OFF_W + (size_t)(b * 4 + gu) * 592;  // uniform

  const int ph = 63 - h, pw = 63 - w;

  if (bru == 0) {
    // ===== attn1 (5x5) =====
    const int bih5 = ph - min(max(ph - 2, 0), 59);
    const int biw5 = pw - min(max(pw - 2, 0), 59);
    const int si5 = min(max(h - 2, 0), 59), sj5 = min(max(w - 2, 0), 59);
    float l1[25];
#pragma unroll
    for (int o = 0; o < 25; o++) {
      const float* wo = Wr + o * 8;
      float s = proj_b[o];
#pragma unroll
      for (int c = 0; c < 8; c++) s += wo[c] * q8[c];
      l1[o] = s;
    }
    const float* rp1 = s_rpb1 + gu * 81 + bih5 * 9 + biw5;
#pragma unroll
    for (int ki = 0; ki < 5; ki++)
#pragma unroll
      for (int kj = 0; kj < 5; kj++) l1[ki * 5 + kj] += rp1[ki * 9 + kj];

    float mx;
    TREE25(FMAXOP, l1, mx);
#pragma unroll
    for (int o = 0; o < 25; o++) l1[o] = __expf(l1[o] - mx);
    float sum;
    TREE25(FADDOP, l1, sum);
    const float inv = 1.f / sum;

    float acc[8];
#pragma unroll
    for (int c = 0; c < 8; c++) acc[c] = 0.f;
    const float* vb = xb + gu * 8 * 4096;
#pragma unroll
    for (int i = 0; i < 5; i++) {
      const float a0 = l1[i * 5 + 0], a1 = l1[i * 5 + 1], a2 = l1[i * 5 + 2];
      const float a3 = l1[i * 5 + 3], a4 = l1[i * 5 + 4];
      const float* vr0 = vb + (si5 + i) * 64 + sj5;
#pragma unroll
      for (int c = 0; c < 8; c++) {
        const float* vr = vr0 + c * 4096;
        const f4u f = *(const f4u*)vr;
        const float v4 = vr[4];
        acc[c] += a0 * f.x + a1 * f.y + a2 * f.z + a3 * f.w + a4 * v4;
      }
    }
#pragma unroll
    for (int c = 0; c < 8; c++) s_val[(gu * 8 + c) * 64 + w] = acc[c] * inv;
  } else {
    // ===== attn2 (7x7) =====
    const int bih7 = ph - min(max(ph - 3, 0), 57);
    const int biw7 = pw - min(max(pw - 3, 0), 57);
    const int si7 = min(max(h - 3, 0), 57), sj7 = min(max(w - 3, 0), 57);
    float l2[49];
#pragma unroll
    for (int o = 0; o < 49; o++) {
      const float* wo = Wr + (25 + o) * 8;
      float s = proj_b[25 + o];
#pragma unroll
      for (int c = 0; c < 8; c++) s += wo[c] * q8[c];
      l2[o] = s;
    }
    const float* rp2 = s_rpb2 + gu * 169 + bih7 * 13 + biw7;
#pragma unroll
    for (int ki = 0; ki < 7; ki++)
#pragma unroll
      for (int kj = 0; kj < 7; kj++) l2[ki * 7 + kj] += rp2[ki * 13 + kj];

    float mx;
    TREE49(FMAXOP, l2, mx);
#pragma unroll
    for (int o = 0; o < 49; o++) l2[o] = __expf(l2[o] - mx);
    float sum;
    TREE49(FADDOP, l2, sum);
    const float inv = 1.f / sum;

    float acc[8];
#pragma unroll
    for (int c = 0; c < 8; c++) acc[c] = 0.f;
    const float* vb = xb + (32 + gu * 8) * 4096;
#pragma unroll
    for (int i = 0; i < 7; i++) {
      const float a0 = l2[i * 7 + 0], a1 = l2[i * 7 + 1], a2 = l2[i * 7 + 2];
      const float a3 = l2[i * 7 + 3], a4 = l2[i * 7 + 4], a5 = l2[i * 7 + 5];
      const float a6 = l2[i * 7 + 6];
      const float* vr0 = vb + (si7 + i) * 64 + sj7;
#pragma unroll
      for (int c = 0; c < 8; c++) {
        const float* vr = vr0 + c * 4096;
        const f4u fa = *(const f4u*)vr;        // j 0..3
        const f4u fb = *(const f4u*)(vr + 3);  // j 3..6
        acc[c] += a0 * fa.x + a1 * fa.y + a2 * fa.z + a3 * fa.w +
                  a4 * fb.y + a5 * fb.z + a6 * fb.w;
      }
    }
#pragma unroll
    for (int c = 0; c < 8; c++) s_val[(32 + gu * 8 + c) * 64 + w] = acc[c] * inv;
  }

  __syncthreads();

  // ===== fused final conv1x1 (64->64) + BN =====
  {
    const int ogu = __builtin_amdgcn_readfirstlane(tid >> 6);  // 0..7
    float facc[8];
#pragma unroll
    for (int oo = 0; oo < 8; oo++) facc[oo] = 0.f;
    const float* dyt = ws + OFF_DYT + ogu * 8;
#pragma unroll
    for (int i = 0; i < 64; i++) {
      const float v = s_val[i * 64 + w];
#pragma unroll
      for (int oo = 0; oo < 8; oo++) facc[oo] += dyt[i * 64 + oo] * v;
    }
#pragma unroll
    for (int oo = 0; oo < 8; oo++) {
      const int oc = ogu * 8 + oo;
      const float sc = dy_g[oc] * rsqrtf(dy_v[oc] + EPSV);
      out[((size_t)(b * 64 + oc)) * 4096 + h * 64 + w] =
          (facc[oo] - dy_m[oc]) * sc + dy_b[oc];
    }
  }
}

// ---------------------------------------------------------------------------
extern "C" void kernel_launch(void* const* d_in, const int* in_sizes, int n_in,
                              void* d_out, int out_size, void* d_ws, size_t ws_size,
                              hipStream_t stream)
{
  const float* x      = (const float*)d_in[0];
  const float* wq_w   = (const float*)d_in[1];
  const float* wq_g   = (const float*)d_in[2];
  const float* wq_b   = (const float*)d_in[3];
  const float* wq_m   = (const float*)d_in[4];
  const float* wq_v   = (const float*)d_in[5];
  const float* wk_w   = (const float*)d_in[6];
  const float* wk_g   = (const float*)d_in[7];
  const float* wk_b   = (const float*)d_in[8];
  const float* wk_m   = (const float*)d_in[9];
  const float* wk_v   = (const float*)d_in[10];
  const float* proj_w = (const float*)d_in[11];
  const float* proj_b = (const float*)d_in[12];
  const float* rpb1   = (const float*)d_in[13];
  const float* rpb2   = (const float*)d_in[14];
  const float* dy_w   = (const float*)d_in[15];
  const float* dy_g   = (const float*)d_in[16];
  const float* dy_b   = (const float*)d_in[17];
  const float* dy_m   = (const float*)d_in[18];
  const float* dy_v   = (const float*)d_in[19];

  float* ws = (float*)d_ws;

  pool_prep_kernel<<<76, 256, 0, stream>>>(x, wk_w, wk_g, wk_b, wk_m, wk_v,
                                           wq_w, dy_w, ws);
  fold_w_kernel<<<32, 256, 0, stream>>>(proj_w, ws, ws + OFF_W);
  contmix_main<<<512, 512, 0, stream>>>(x, wq_g, wq_b, wq_m, wq_v,
                                        proj_b, rpb1, rpb2,
                                        dy_g, dy_b, dy_m, dy_v,
                                        ws, (float*)d_out);
}

// Round 4
// 161.931 us; speedup vs baseline: 1.2155x; 1.0238x over previous
//
#include <hip/hip_runtime.h>

#define EPSV 1e-5f

// Workspace layout (floats):
//   kbuf @ 0     : [b][g][c][l]  8*4*8*49 = 12544
//   W    @ 12544 : [b][g][o<74][c<8]      = 18944   (W = proj_w @ k^T)
//   wqT  @ 31488 : [i][o] 32*32           = 1024
//   dyT  @ 32512 : [i][o] 64*64           = 4096
#define OFF_W    12544
#define OFF_WQT  31488
#define OFF_DYT  32512

typedef float f4u __attribute__((ext_vector_type(4), aligned(4)));

// Tree reductions (depth ~6 instead of serial 25/49 chains).
#define FMAXOP(a, b) fmaxf((a), (b))
#define FADDOP(a, b) ((a) + (b))

#define TREE25(op, arr, res)                                         \
  {                                                                  \
    float u_[13];                                                    \
    _Pragma("unroll") for (int i_ = 0; i_ < 12; i_++)                \
        u_[i_] = op(arr[i_], arr[i_ + 12]);                          \
    u_[12] = arr[24];                                                \
    _Pragma("unroll") for (int i_ = 0; i_ < 6; i_++)                 \
        u_[i_] = op(u_[i_], u_[i_ + 6]);                             \
    _Pragma("unroll") for (int i_ = 0; i_ < 3; i_++)                 \
        u_[i_] = op(u_[i_], u_[i_ + 3]);                             \
    res = op(op(op(u_[0], u_[1]), u_[2]), u_[12]);                   \
  }

#define TREE49(op, arr, res)                                         \
  {                                                                  \
    float u_[25];                                                    \
    _Pragma("unroll") for (int i_ = 0; i_ < 24; i_++)                \
        u_[i_] = op(arr[i_], arr[i_ + 24]);                          \
    u_[24] = arr[48];                                                \
    _Pragma("unroll") for (int i_ = 0; i_ < 12; i_++)                \
        u_[i_] = op(u_[i_], u_[i_ + 12]);                            \
    _Pragma("unroll") for (int i_ = 0; i_ < 6; i_++)                 \
        u_[i_] = op(u_[i_], u_[i_ + 6]);                             \
    _Pragma("unroll") for (int i_ = 0; i_ < 3; i_++)                 \
        u_[i_] = op(u_[i_], u_[i_ + 3]);                             \
    res = op(op(op(u_[0], u_[1]), u_[2]), u_[24]);                   \
  }

// ---------------------------------------------------------------------------
// Blocks 0..55: pool kctx (ch 32..63) to 7x7, wk conv1x1 + BN.
// Blocks 56..75: weight transposes (wqT, dyT).
// ---------------------------------------------------------------------------
__global__ __launch_bounds__(256) void pool_prep_kernel(
    const float* __restrict__ x,
    const float* __restrict__ wk_w, const float* __restrict__ wk_g,
    const float* __restrict__ wk_b, const float* __restrict__ wk_m,
    const float* __restrict__ wk_v,
    const float* __restrict__ wq_w, const float* __restrict__ dy_w,
    float* __restrict__ ws)
{
  const int bid = blockIdx.x;
  const int tid = threadIdx.x;

  if (bid >= 56) {
    const int t = (bid - 56) * 256 + tid;
    float* wqT = ws + OFF_WQT;
    float* dyT = ws + OFF_DYT;
    if (t < 1024) {
      const int i = t >> 5, o = t & 31;
      wqT[t] = wq_w[o * 32 + i];
    } else {
      const int t2 = t - 1024;  // 0..4095
      const int i = t2 >> 6, o = t2 & 63;
      dyT[t2] = dy_w[o * 64 + i];
    }
    return;
  }

  float* kbuf = ws;
  const int b = bid / 7;
  const int p = bid % 7;
  __shared__ float s_tmp[32 * 64];
  __shared__ float s_kp[32 * 7];

  const int sh = (p * 64) / 7, eh = ((p + 1) * 64 + 6) / 7;
  const float invH = 1.0f / (float)(eh - sh);
  for (int idx = tid; idx < 2048; idx += 256) {
    const int c = idx >> 6, ww = idx & 63;
    const float* xp = x + ((size_t)(b * 64 + 32 + c)) * 4096 + ww;
    float s = 0.f;
    for (int hh = sh; hh < eh; ++hh) s += xp[hh * 64];
    s_tmp[idx] = s * invH;
  }
  __syncthreads();
  if (tid < 224) {
    const int c = tid / 7, q = tid % 7;
    const int sw = (q * 64) / 7, ew = ((q + 1) * 64 + 6) / 7;
    float s = 0.f;
    for (int ww = sw; ww < ew; ++ww) s += s_tmp[c * 64 + ww];
    s_kp[c * 7 + q] = s / (float)(ew - sw);
  }
  __syncthreads();
  if (tid < 224) {
    const int o = tid / 7, q = tid % 7;
    float s = 0.f;
#pragma unroll
    for (int i = 0; i < 32; i++) s += wk_w[o * 32 + i] * s_kp[i * 7 + q];
    const float sc = wk_g[o] * rsqrtf(wk_v[o] + EPSV);
    const int g = o >> 3, c = o & 7, l = p * 7 + q;
    kbuf[(((size_t)b * 4 + g) * 8 + c) * 49 + l] =
        (s - wk_m[o]) * sc + wk_b[o];
  }
}

// ---------------------------------------------------------------------------
// W[bg][o][c] = sum_l proj_w[o][l] * k[bg][c][l].  32 blocks, 256 threads.
// ---------------------------------------------------------------------------
__global__ __launch_bounds__(256) void fold_w_kernel(
    const float* __restrict__ proj_w, const float* __restrict__ ws_in,
    float* __restrict__ Wout)
{
  const int bg = blockIdx.x;
  const int tid = threadIdx.x;
  __shared__ float s_k[392];
  for (int i = tid; i < 392; i += 256) s_k[i] = ws_in[(size_t)bg * 392 + i];
  __syncthreads();
  for (int idx = tid; idx < 592; idx += 256) {
    const int o = idx >> 3, c = idx & 7;
    float s = 0.f;
#pragma unroll
    for (int l = 0; l < 49; l++) s += proj_w[o * 49 + l] * s_k[c * 49 + l];
    Wout[(size_t)bg * 592 + idx] = s;
  }
}

// ---------------------------------------------------------------------------
// Fused main. Block = 512 = 2 branches x 4 heads x 64 cols, one row.
// q-input row x[b][0:32][h][:] is staged into LDS cooperatively BEFORE the
// existing rpb barrier (one f4 per thread) — both branch halves then read it
// from LDS, removing the 2x-redundant 32-strided-load q phase without adding
// any synchronization (r1's failure mode). Same values, same FMA order.
// ---------------------------------------------------------------------------
__global__ __launch_bounds__(512, 4) void contmix_main(
    const float* __restrict__ x,
    const float* __restrict__ wq_g, const float* __restrict__ wq_b,
    const float* __restrict__ wq_m, const float* __restrict__ wq_v,
    const float* __restrict__ proj_b,
    const float* __restrict__ rpb1, const float* __restrict__ rpb2,
    const float* __restrict__ dy_g, const float* __restrict__ dy_b,
    const float* __restrict__ dy_m, const float* __restrict__ dy_v,
    const float* __restrict__ ws,
    float* __restrict__ out)
{
  __shared__ float s_rpb1[4 * 81];
  __shared__ float s_rpb2[4 * 169];
  __shared__ float s_val[64 * 64];  // [ch][w]
  __shared__ float s_xq[32 * 64];   // q-input row x[b][0:32][h][:]

  const int bx = blockIdx.x;
  const int b = bx >> 6;
  const int h = bx & 63;
  const int tid = threadIdx.x;
  const int w = tid & 63;
  const int bru = __builtin_amdgcn_readfirstlane(tid >> 8);
  const int gu  = __builtin_amdgcn_readfirstlane((tid >> 6) & 3);

  const float* xb = x + (size_t)b * 64 * 4096;

  // stage q-input row: 2048 floats, one f4 per thread, coalesced
  {
    const int c = tid >> 4;            // 0..31
    const int w4 = (tid & 15) * 4;     // 0..60
    *(f4u*)&s_xq[c * 64 + w4] = *(const f4u*)&xb[c * 4096 + h * 64 + w4];
  }
  for (int i = tid; i < 324; i += 512) s_rpb1[i] = rpb1[i];
  for (int i = tid; i < 676; i += 512) s_rpb2[i] = rpb2[i];
  __syncthreads();

  // ---- q = BN(wq @ x[0:32]) * SCALE ----
  float q8[8];
#pragma unroll
  for (int o = 0; o < 8; o++) q8[o] = 0.f;
  {
    const float* wqt = ws + OFF_WQT + gu * 8;
#pragma unroll
    for (int i = 0; i < 32; i++) {
      const float xv = s_xq[i * 64 + w];
#pragma unroll
      for (int o = 0; o < 8; o++) q8[o] += wqt[i * 32 + o] * xv;
    }
#pragma unroll
    for (int o = 0; o < 8; o++) {
      const int oc = gu * 8 + o;
      const float s = wq_g[oc] * rsqrtf(wq_v[oc] + EPSV);
      q8[o] = (q8[o] * s + (wq_b[oc] - wq_m[oc] * s)) * 0.25f;
    }
  }

  const float* Wr = ws + OFF_W + (size_t)(b * 4 + gu) * 592;  // uniform

  const int ph = 63 - h, pw = 63 - w;

  if (bru == 0) {
    // ===== attn1 (5x5) =====
    const int bih5 = ph - min(max(ph - 2, 0), 59);
    const int biw5 = pw - min(max(pw - 2, 0), 59);
    const int si5 = min(max(h - 2, 0), 59), sj5 = min(max(w - 2, 0), 59);
    float l1[25];
#pragma unroll
    for (int o = 0; o < 25; o++) {
      const float* wo = Wr + o * 8;
      float s = proj_b[o];
#pragma unroll
      for (int c = 0; c < 8; c++) s += wo[c] * q8[c];
      l1[o] = s;
    }
    const float* rp1 = s_rpb1 + gu * 81 + bih5 * 9 + biw5;
#pragma unroll
    for (int ki = 0; ki < 5; ki++)
#pragma unroll
      for (int kj = 0; kj < 5; kj++) l1[ki * 5 + kj] += rp1[ki * 9 + kj];

    float mx;
    TREE25(FMAXOP, l1, mx);
#pragma unroll
    for (int o = 0; o < 25; o++) l1[o] = __expf(l1[o] - mx);
    float sum;
    TREE25(FADDOP, l1, sum);
    const float inv = 1.f / sum;

    float acc[8];
#pragma unroll
    for (int c = 0; c < 8; c++) acc[c] = 0.f;
    const float* vb = xb + gu * 8 * 4096;
#pragma unroll
    for (int i = 0; i < 5; i++) {
      const float a0 = l1[i * 5 + 0], a1 = l1[i * 5 + 1], a2 = l1[i * 5 + 2];
      const float a3 = l1[i * 5 + 3], a4 = l1[i * 5 + 4];
      const float* vr0 = vb + (si5 + i) * 64 + sj5;
#pragma unroll
      for (int c = 0; c < 8; c++) {
        const float* vr = vr0 + c * 4096;
        const f4u f = *(const f4u*)vr;
        const float v4 = vr[4];
        acc[c] += a0 * f.x + a1 * f.y + a2 * f.z + a3 * f.w + a4 * v4;
      }
    }
#pragma unroll
    for (int c = 0; c < 8; c++) s_val[(gu * 8 + c) * 64 + w] = acc[c] * inv;
  } else {
    // ===== attn2 (7x7) =====
    const int bih7 = ph - min(max(ph - 3, 0), 57);
    const int biw7 = pw - min(max(pw - 3, 0), 57);
    const int si7 = min(max(h - 3, 0), 57), sj7 = min(max(w - 3, 0), 57);
    float l2[49];
#pragma unroll
    for (int o = 0; o < 49; o++) {
      const float* wo = Wr + (25 + o) * 8;
      float s = proj_b[25 + o];
#pragma unroll
      for (int c = 0; c < 8; c++) s += wo[c] * q8[c];
      l2[o] = s;
    }
    const float* rp2 = s_rpb2 + gu * 169 + bih7 * 13 + biw7;
#pragma unroll
    for (int ki = 0; ki < 7; ki++)
#pragma unroll
      for (int kj = 0; kj < 7; kj++) l2[ki * 7 + kj] += rp2[ki * 13 + kj];

    float mx;
    TREE49(FMAXOP, l2, mx);
#pragma unroll
    for (int o = 0; o < 49; o++) l2[o] = __expf(l2[o] - mx);
    float sum;
    TREE49(FADDOP, l2, sum);
    const float inv = 1.f / sum;

    float acc[8];
#pragma unroll
    for (int c = 0; c < 8; c++) acc[c] = 0.f;
    const float* vb = xb + (32 + gu * 8) * 4096;
#pragma unroll
    for (int i = 0; i < 7; i++) {
      const float a0 = l2[i * 7 + 0], a1 = l2[i * 7 + 1], a2 = l2[i * 7 + 2];
      const float a3 = l2[i * 7 + 3], a4 = l2[i * 7 + 4], a5 = l2[i * 7 + 5];
      const float a6 = l2[i * 7 + 6];
      const float* vr0 = vb + (si7 + i) * 64 + sj7;
#pragma unroll
      for (int c = 0; c < 8; c++) {
        const float* vr = vr0 + c * 4096;
        const f4u fa = *(const f4u*)vr;        // j 0..3
        const f4u fb = *(const f4u*)(vr + 3);  // j 3..6
        acc[c] += a0 * fa.x + a1 * fa.y + a2 * fa.z + a3 * fa.w +
                  a4 * fb.y + a5 * fb.z + a6 * fb.w;
      }
    }
#pragma unroll
    for (int c = 0; c < 8; c++) s_val[(32 + gu * 8 + c) * 64 + w] = acc[c] * inv;
  }

  __syncthreads();

  // ===== fused final conv1x1 (64->64) + BN =====
  {
    const int ogu = __builtin_amdgcn_readfirstlane(tid >> 6);  // 0..7
    float facc[8];
#pragma unroll
    for (int oo = 0; oo < 8; oo++) facc[oo] = 0.f;
    const float* dyt = ws + OFF_DYT + ogu * 8;
#pragma unroll
    for (int i = 0; i < 64; i++) {
      const float v = s_val[i * 64 + w];
#pragma unroll
      for (int oo = 0; oo < 8; oo++) facc[oo] += dyt[i * 64 + oo] * v;
    }
#pragma unroll
    for (int oo = 0; oo < 8; oo++) {
      const int oc = ogu * 8 + oo;
      const float sc = dy_g[oc] * rsqrtf(dy_v[oc] + EPSV);
      out[((size_t)(b * 64 + oc)) * 4096 + h * 64 + w] =
          (facc[oo] - dy_m[oc]) * sc + dy_b[oc];
    }
  }
}

// ---------------------------------------------------------------------------
extern "C" void kernel_launch(void* const* d_in, const int* in_sizes, int n_in,
                              void* d_out, int out_size, void* d_ws, size_t ws_size,
                              hipStream_t stream)
{
  const float* x      = (const float*)d_in[0];
  const float* wq_w   = (const float*)d_in[1];
  const float* wq_g   = (const float*)d_in[2];
  const float* wq_b   = (const float*)d_in[3];
  const float* wq_m   = (const float*)d_in[4];
  const float* wq_v   = (const float*)d_in[5];
  const float* wk_w   = (const float*)d_in[6];
  const float* wk_g   = (const float*)d_in[7];
  const float* wk_b   = (const float*)d_in[8];
  const float* wk_m   = (const float*)d_in[9];
  const float* wk_v   = (const float*)d_in[10];
  const float* proj_w = (const float*)d_in[11];
  const float* proj_b = (const float*)d_in[12];
  const float* rpb1   = (const float*)d_in[13];
  const float* rpb2   = (const float*)d_in[14];
  const float* dy_w   = (const float*)d_in[15];
  const float* dy_g   = (const float*)d_in[16];
  const float* dy_b   = (const float*)d_in[17];
  const float* dy_m   = (const float*)d_in[18];
  const float* dy_v   = (const float*)d_in[19];

  float* ws = (float*)d_ws;

  pool_prep_kernel<<<76, 256, 0, stream>>>(x, wk_w, wk_g, wk_b, wk_m, wk_v,
                                           wq_w, dy_w, ws);
  fold_w_kernel<<<32, 256, 0, stream>>>(proj_w, ws, ws + OFF_W);
  contmix_main<<<512, 512, 0, stream>>>(x, wq_g, wq_b, wq_m, wq_v,
                                        proj_b, rpb1, rpb2,
                                        dy_g, dy_b, dy_m, dy_v,
                                        ws, (float*)d_out);
}